// Round 5
// baseline (283.510 us; speedup 1.0000x reference)
//
#include <hip/hip_runtime.h>
#include <math.h>

#define N_NODES 20000
#define N_EDGES 160000

#define PI_F 3.14159265358979323846f
#define LN2_F 0.69314718055994530942f

#define XSTR 656           // X row stride in bf16 elems (1312 B rows, 16B aligned)
#define W1PK 43008         // 21 ksteps * 4 colfrags * 64 lanes * 8 (ushort units)
#define W23PK 4096         // 2 ksteps  * 4 * 64 * 8
#define WPK_LAYER 51200    // per-layer packed weights (ushort units)

typedef short short8v __attribute__((ext_vector_type(8)));
typedef float f32x4 __attribute__((ext_vector_type(4)));
typedef unsigned short u16;

__device__ __forceinline__ float sspf(float x) {
    return fmaxf(x, 0.0f) + log1pf(expf(-fabsf(x))) - LN2_F;
}
// round-to-nearest-even f32 -> bf16
__device__ __forceinline__ u16 f2bf(float f) {
    unsigned int u = __float_as_uint(f);
    return (u16)((u + 0x7fffu + ((u >> 16) & 1u)) >> 16);
}
__device__ __forceinline__ float bflo(unsigned int u) { return __uint_as_float(u << 16); }
__device__ __forceinline__ float bfhi(unsigned int u) { return __uint_as_float(u & 0xffff0000u); }

// ---------------------------------------------------------------------------
// rb_pk[e] = bf16x8 of switch[e] * sqrt(2/5) * sin((n+1) pi r / 5) / r
// (uint4 = 16B/lane stores: clean write path)
// ---------------------------------------------------------------------------
__global__ __launch_bounds__(256) void edge_rb_kernel(
    const float* __restrict__ dist,
    const float* __restrict__ sw,
    unsigned int* __restrict__ rbpk)   // E x 4 uints
{
    int e = blockIdx.x * blockDim.x + threadIdx.x;
    if (e >= N_EDGES) return;
    float r = dist[e];
    float c = sqrtf(2.0f / 5.0f) / r * sw[e];
    float out[8];
    #pragma unroll
    for (int n = 0; n < 8; ++n)
        out[n] = c * sinf((float)(n + 1) * PI_F * r * 0.2f);
    uint4 pk;
    pk.x = (unsigned int)f2bf(out[0]) | ((unsigned int)f2bf(out[1]) << 16);
    pk.y = (unsigned int)f2bf(out[2]) | ((unsigned int)f2bf(out[3]) << 16);
    pk.z = (unsigned int)f2bf(out[4]) | ((unsigned int)f2bf(out[5]) << 16);
    pk.w = (unsigned int)f2bf(out[6]) | ((unsigned int)f2bf(out[7]) << 16);
    *reinterpret_cast<uint4*>(rbpk + (size_t)e * 4) = pk;
}

// ---------------------------------------------------------------------------
// CSR offsets from sorted edge_src
// ---------------------------------------------------------------------------
__global__ __launch_bounds__(256) void row_start_kernel(
    const int* __restrict__ src, int* __restrict__ row)
{
    int i = blockIdx.x * blockDim.x + threadIdx.x;
    if (i > N_NODES) return;
    int lo = 0, hi = N_EDGES;
    while (lo < hi) {
        int mid = (lo + hi) >> 1;
        if (src[mid] < i) lo = mid + 1; else hi = mid;
    }
    row[i] = lo;
}

// ---------------------------------------------------------------------------
// xi = W_species[species]   (float4 stores: clean)
// ---------------------------------------------------------------------------
__global__ __launch_bounds__(256) void xi_init_kernel(
    const int* __restrict__ species,
    const float* __restrict__ Wsp,
    float* __restrict__ xi)
{
    int idx = blockIdx.x * blockDim.x + threadIdx.x;
    if (idx >= N_NODES * 16) return;
    int node = idx >> 4;
    int c4 = idx & 15;
    int sp = species[node];
    reinterpret_cast<float4*>(xi)[idx] =
        reinterpret_cast<const float4*>(Wsp + (size_t)sp * 64)[c4];
}

// ---------------------------------------------------------------------------
// Pack FC weights -> bf16 B-fragment layout for mfma_f32_16x16x32_bf16.
// (runs once; u16 scalar stores acceptable)
// ---------------------------------------------------------------------------
__global__ __launch_bounds__(256) void pack_w_kernel(
    const float* __restrict__ fcW1,
    const float* __restrict__ fcW2,
    const float* __restrict__ fcW3,
    u16* __restrict__ Wpk)
{
    int idx = blockIdx.x * 256 + threadIdx.x;
    if (idx >= 3 * WPK_LAYER) return;
    int layer = idx / WPK_LAYER;
    int r = idx - layer * WPK_LAYER;
    float val = 0.0f;
    if (r < W1PK) {
        int e = r;
        int j = e & 7, lane = (e >> 3) & 63, c16 = (e >> 9) & 3, ks = e >> 11;
        int k = ks * 32 + (lane >> 4) * 8 + j;
        int colm = c16 * 16 + (lane & 15);
        if (k < 640) {
            int ss = k / 40, rem = k - ss * 40;
            int nn = rem / 5, bb = rem - nn * 5;
            val = fcW1[(size_t)layer * 656 * 64 + (size_t)(nn * 80 + ss * 5 + bb) * 64 + colm];
        } else if (k < 656) {
            val = fcW1[(size_t)layer * 656 * 64 + (size_t)k * 64 + colm];
        }
    } else {
        bool is2 = (r < W1PK + W23PK);
        const float* W = is2 ? fcW2 : fcW3;
        int e = is2 ? (r - W1PK) : (r - W1PK - W23PK);
        int j = e & 7, lane = (e >> 3) & 63, c16 = (e >> 9) & 3, ks = e >> 11;
        int k = ks * 32 + (lane >> 4) * 8 + j;
        int colm = c16 * 16 + (lane & 15);
        val = W[(size_t)layer * 64 * 64 + (size_t)k * 64 + colm];
    }
    Wpk[(size_t)layer * WPK_LAYER + r] = f2bf(val);
}

// ---------------------------------------------------------------------------
// h = xi @ Wl[l] + bl[l]   (N x 32).  Thread owns 1 node x 4 cols -> float4
// store (16B/lane: clean write path).
// ---------------------------------------------------------------------------
__global__ __launch_bounds__(256) void h_kernel(
    const float* __restrict__ xi,
    const float* __restrict__ Wl,
    const float* __restrict__ bl,
    float* __restrict__ h)
{
    __shared__ float xs[32 * 64];
    __shared__ float ws[64 * 32];
    int tid = threadIdx.x;
    int nb = blockIdx.x * 32;

    const float4* xsrc = reinterpret_cast<const float4*>(xi + (size_t)nb * 64);
    float4* xd = reinterpret_cast<float4*>(xs);
    #pragma unroll
    for (int i = 0; i < 2; ++i) xd[tid + i * 256] = xsrc[tid + i * 256];
    const float4* wsrc = reinterpret_cast<const float4*>(Wl);
    float4* wd = reinterpret_cast<float4*>(ws);
    #pragma unroll
    for (int i = 0; i < 2; ++i) wd[tid + i * 256] = wsrc[tid + i * 256];
    __syncthreads();

    int c4g = tid & 7;     // col group (4 cols)
    int nrow = tid >> 3;   // node within tile (0..31)
    float4 acc = *reinterpret_cast<const float4*>(bl + c4g * 4);
    const float* xr = xs + nrow * 64;
    #pragma unroll 8
    for (int j = 0; j < 64; ++j) {
        float xv = xr[j];
        float4 wv = *reinterpret_cast<const float4*>(ws + j * 32 + c4g * 4);
        acc.x = fmaf(xv, wv.x, acc.x);
        acc.y = fmaf(xv, wv.y, acc.y);
        acc.z = fmaf(xv, wv.z, acc.z);
        acc.w = fmaf(xv, wv.w, acc.w);
    }
    *reinterpret_cast<float4*>(h + (size_t)(nb + nrow) * 32 + c4g * 4) = acc;
}

// ---------------------------------------------------------------------------
// Aggregation: one wave per node. lane = (es 0..3)<<4 | (s 0..15).
// Accumulate, butterfly-reduce, stage rows in LDS, then the whole BLOCK
// writes its 4 rows (5248 B) as uint4 (16B/lane) stores.
// Row layout: f = s*40 + n*5 + b for f<640; cols 640..655 = si = h[:, :16].
// ---------------------------------------------------------------------------
__global__ __launch_bounds__(256) void agg_kernel(
    const unsigned int* __restrict__ rbpk,  // E x 4 (bf16 pairs)
    const float* __restrict__ bo,           // E x 5
    const int* __restrict__ row,
    const int* __restrict__ dst,
    const float* __restrict__ h,            // N x 32
    u16* __restrict__ X)                    // N x 656 (bf16)
{
    __shared__ unsigned int rowbuf[4][332];   // 328 dwords used; 1328B row (16B-aligned)

    int tid = threadIdx.x;
    int wv = tid >> 6;                 // wave in block
    int wid = (blockIdx.x << 2) | wv;  // node (grid exact: 5000*4 = 20000)
    int lane = tid & 63;
    int s = lane & 15;
    int es = lane >> 4;

    int e0 = row[wid], e1 = row[wid + 1];

    float acc[40];
    #pragma unroll
    for (int j = 0; j < 40; ++j) acc[j] = 0.0f;

    for (int e = e0 + es; e < e1; e += 4) {
        int d = dst[e];
        float mi = h[(size_t)d * 32 + 16 + s];
        uint4 rv = *reinterpret_cast<const uint4*>(rbpk + (size_t)e * 4);
        const float* bp = bo + (size_t)e * 5;
        float bm0 = bp[0] * mi, bm1 = bp[1] * mi, bm2 = bp[2] * mi,
              bm3 = bp[3] * mi, bm4 = bp[4] * mi;
        float rr[8] = {bflo(rv.x), bfhi(rv.x), bflo(rv.y), bfhi(rv.y),
                       bflo(rv.z), bfhi(rv.z), bflo(rv.w), bfhi(rv.w)};
        #pragma unroll
        for (int n = 0; n < 8; ++n) {
            acc[n * 5 + 0] = fmaf(rr[n], bm0, acc[n * 5 + 0]);
            acc[n * 5 + 1] = fmaf(rr[n], bm1, acc[n * 5 + 1]);
            acc[n * 5 + 2] = fmaf(rr[n], bm2, acc[n * 5 + 2]);
            acc[n * 5 + 3] = fmaf(rr[n], bm3, acc[n * 5 + 3]);
            acc[n * 5 + 4] = fmaf(rr[n], bm4, acc[n * 5 + 4]);
        }
    }
    #pragma unroll
    for (int j = 0; j < 40; ++j) {
        acc[j] += __shfl_xor(acc[j], 16, 64);
        acc[j] += __shfl_xor(acc[j], 32, 64);
    }

    // ---- stage into LDS row buffer ----
    unsigned int* rb = rowbuf[wv];
    unsigned int* op = rb + (s * 20 + es * 5);
    #pragma unroll
    for (int m = 0; m < 5; ++m) {
        int j = es * 10 + 2 * m;
        op[m] = (unsigned int)f2bf(acc[j]) |
                ((unsigned int)f2bf(acc[j + 1]) << 16);
    }
    // si: dwords 320..327 (16 bf16 from h[wid, 0:16])
    if (es == 2 && s < 8) {
        float v0 = h[(size_t)wid * 32 + 2 * s];
        float v1 = h[(size_t)wid * 32 + 2 * s + 1];
        rb[320 + s] = (unsigned int)f2bf(v0) | ((unsigned int)f2bf(v1) << 16);
    }
    __syncthreads();

    // ---- block-wide uint4 write-out: 4 rows = 328 x 16B, all aligned ----
    unsigned int* Xd = reinterpret_cast<unsigned int*>(X) + (size_t)(blockIdx.x << 2) * 328;
    #pragma unroll
    for (int rd = 0; rd < 2; ++rd) {
        int f = rd * 256 + tid;            // float4 index within block region
        if (f < 328) {
            int r = f / 82;                // row (82 float4 per 1312B row)
            int dwo = (f - r * 82) * 4;    // dword offset in row (16B-aligned)
            uint4 v = *reinterpret_cast<const uint4*>(&rowbuf[r][dwo]);
            *reinterpret_cast<uint4*>(Xd + (size_t)f * 4) = v;
        }
    }
}

// ---------------------------------------------------------------------------
// Fused FC chain via MFMA. Block = 256 thr = 4 waves; 16 nodes per block.
// Epilogue bounces C through f32 LDS so xi update is float4 (16B/lane).
// ---------------------------------------------------------------------------
__global__ __launch_bounds__(256) void fc_kernel(
    const u16* __restrict__ X,      // N x 656 bf16
    const u16* __restrict__ Wpk,    // layer's packed weights
    const float* __restrict__ b1,
    const float* __restrict__ b2,
    const float* __restrict__ b3,
    float* __restrict__ xi)
{
    __shared__ __align__(16) u16 Y1[16 * 72];
    __shared__ __align__(16) u16 Y2[16 * 72];
    __shared__ __align__(16) float Yo[16 * 68];

    int tid = threadIdx.x;
    int w = tid >> 6;
    int l = tid & 63;
    int lrow = l & 15;
    int lk = l >> 4;
    int n0 = blockIdx.x * 16;
    int node = n0 + lrow;
    int col = w * 16 + lrow;

    const u16* Wpk1 = Wpk;
    const u16* Wpk2 = Wpk + W1PK;
    const u16* Wpk3 = Wpk + W1PK + W23PK;

    // ---- FC1: K = 656 (+16 zero-padded via packed-W zeros) ----
    f32x4 acc;
    {
        float bv = b1[col];
        acc[0] = bv; acc[1] = bv; acc[2] = bv; acc[3] = bv;
    }
    const u16* xp = X + (size_t)node * XSTR + lk * 8;
    const u16* wp = Wpk1 + ((size_t)w * 64 + l) * 8;
    #pragma unroll
    for (int ks = 0; ks < 21; ++ks) {
        short8v a = *reinterpret_cast<const short8v*>(xp + ks * 32);
        short8v b = *reinterpret_cast<const short8v*>(wp + (size_t)ks * 2048);
        acc = __builtin_amdgcn_mfma_f32_16x16x32_bf16(a, b, acc, 0, 0, 0);
    }
    #pragma unroll
    for (int q = 0; q < 4; ++q)
        Y1[(lk * 4 + q) * 72 + col] = f2bf(sspf(acc[q]));
    __syncthreads();

    // ---- FC2: K = 64 ----
    {
        float bv = b2[col];
        acc[0] = bv; acc[1] = bv; acc[2] = bv; acc[3] = bv;
    }
    #pragma unroll
    for (int ks = 0; ks < 2; ++ks) {
        short8v a = *reinterpret_cast<const short8v*>(&Y1[lrow * 72 + ks * 32 + lk * 8]);
        short8v b = *reinterpret_cast<const short8v*>(Wpk2 + ((size_t)(ks * 4 + w) * 64 + l) * 8);
        acc = __builtin_amdgcn_mfma_f32_16x16x32_bf16(a, b, acc, 0, 0, 0);
    }
    #pragma unroll
    for (int q = 0; q < 4; ++q)
        Y2[(lk * 4 + q) * 72 + col] = f2bf(sspf(acc[q]));
    __syncthreads();

    // ---- FC3: K = 64 ----
    {
        float bv = b3[col];
        acc[0] = bv; acc[1] = bv; acc[2] = bv; acc[3] = bv;
    }
    #pragma unroll
    for (int ks = 0; ks < 2; ++ks) {
        short8v a = *reinterpret_cast<const short8v*>(&Y2[lrow * 72 + ks * 32 + lk * 8]);
        short8v b = *reinterpret_cast<const short8v*>(Wpk3 + ((size_t)(ks * 4 + w) * 64 + l) * 8);
        acc = __builtin_amdgcn_mfma_f32_16x16x32_bf16(a, b, acc, 0, 0, 0);
    }
    #pragma unroll
    for (int q = 0; q < 4; ++q)
        Yo[(lk * 4 + q) * 68 + col] = acc[q];
    __syncthreads();

    // ---- residual update, float4 per lane ----
    {
        int rr = tid >> 4;      // node row 0..15
        int cc = tid & 15;      // col group (4 cols)
        float4 dv = *reinterpret_cast<const float4*>(Yo + rr * 68 + cc * 4);
        float4* xpn = reinterpret_cast<float4*>(xi + (size_t)(n0 + rr) * 64 + cc * 4);
        float4 o = *xpn;
        o.x += dv.x; o.y += dv.y; o.z += dv.z; o.w += dv.w;
        *xpn = o;
    }
}

// ---------------------------------------------------------------------------
extern "C" void kernel_launch(void* const* d_in, const int* in_sizes, int n_in,
                              void* d_out, int out_size, void* d_ws, size_t ws_size,
                              hipStream_t stream) {
    const int*   species = (const int*)d_in[0];
    const int*   esrc    = (const int*)d_in[1];
    const int*   edst    = (const int*)d_in[2];
    const float* dist    = (const float*)d_in[3];
    const float* sw      = (const float*)d_in[4];
    const float* bo      = (const float*)d_in[5];
    const float* Wsp     = (const float*)d_in[6];
    const float* Wl      = (const float*)d_in[7];
    const float* bl      = (const float*)d_in[8];
    const float* fcW1    = (const float*)d_in[9];
    const float* fcb1    = (const float*)d_in[10];
    const float* fcW2    = (const float*)d_in[11];
    const float* fcb2    = (const float*)d_in[12];
    const float* fcW3    = (const float*)d_in[13];
    const float* fcb3    = (const float*)d_in[14];
    float* xi = (float*)d_out;

    char* ws = (char*)d_ws;
    unsigned int* rbpk = (unsigned int*)ws;            //  2,560,000 B
    int*          rowp = (int*)(ws + 2560000);         //     80,128 B
    float*        h    = (float*)(ws + 2640128);       //  2,560,000 B
    u16*          X    = (u16*)(ws + 5200128);         // 26,240,064 B (+slack)
    u16*          Wpk  = (u16*)(ws + 31440192);        //    307,200 B

    hipLaunchKernelGGL(edge_rb_kernel, dim3(625), dim3(256), 0, stream,
                       dist, sw, rbpk);
    hipLaunchKernelGGL(row_start_kernel, dim3(79), dim3(256), 0, stream,
                       esrc, rowp);
    hipLaunchKernelGGL(xi_init_kernel, dim3(1250), dim3(256), 0, stream,
                       species, Wsp, xi);
    hipLaunchKernelGGL(pack_w_kernel, dim3(600), dim3(256), 0, stream,
                       fcW1, fcW2, fcW3, Wpk);

    for (int l = 0; l < 3; ++l) {
        hipLaunchKernelGGL(h_kernel, dim3(625), dim3(256), 0, stream,
                           xi, Wl + (size_t)l * 64 * 32, bl + (size_t)l * 32, h);
        hipLaunchKernelGGL(agg_kernel, dim3(5000), dim3(256), 0, stream,
                           rbpk, bo, rowp, edst, h, X);
        hipLaunchKernelGGL(fc_kernel, dim3(1250), dim3(256), 0, stream,
                           X, Wpk + (size_t)l * WPK_LAYER,
                           fcb1 + (size_t)l * 64, fcb2 + (size_t)l * 64,
                           fcb3 + (size_t)l * 64, xi);
    }
}

// Round 6
// 153.791 us; speedup vs baseline: 1.8435x; 1.8435x over previous
//
#include <hip/hip_runtime.h>
#include <math.h>

#define N_NODES 20000
#define N_EDGES 160000

#define PI_F 3.14159265358979323846f
#define LN2_F 0.69314718055994530942f

#define XSTR 656           // X row stride in bf16 elems (1312 B rows, 16B aligned)
#define W1PK 43008         // 21 ksteps * 4 colfrags * 64 lanes * 8 (ushort units)
#define W23PK 4096         // 2 ksteps  * 4 * 64 * 8
#define WPK_LAYER 51200    // per-layer packed weights (ushort units)

typedef short short8v __attribute__((ext_vector_type(8)));
typedef float f32x4 __attribute__((ext_vector_type(4)));
typedef unsigned short u16;

__device__ __forceinline__ float sspf(float x) {
    return fmaxf(x, 0.0f) + log1pf(expf(-fabsf(x))) - LN2_F;
}
// round-to-nearest-even f32 -> bf16
__device__ __forceinline__ u16 f2bf(float f) {
    unsigned int u = __float_as_uint(f);
    return (u16)((u + 0x7fffu + ((u >> 16) & 1u)) >> 16);
}
__device__ __forceinline__ float bflo(unsigned int u) { return __uint_as_float(u << 16); }
__device__ __forceinline__ float bfhi(unsigned int u) { return __uint_as_float(u & 0xffff0000u); }

// ---------------------------------------------------------------------------
// rb_pk[e] = bf16x8 of switch[e] * sqrt(2/5) * sin((n+1) pi r / 5) / r
// ---------------------------------------------------------------------------
__global__ __launch_bounds__(256) void edge_rb_kernel(
    const float* __restrict__ dist,
    const float* __restrict__ sw,
    unsigned int* __restrict__ rbpk)   // E x 4 uints
{
    int e = blockIdx.x * blockDim.x + threadIdx.x;
    if (e >= N_EDGES) return;
    float r = dist[e];
    float c = sqrtf(2.0f / 5.0f) / r * sw[e];
    float out[8];
    #pragma unroll
    for (int n = 0; n < 8; ++n)
        out[n] = c * sinf((float)(n + 1) * PI_F * r * 0.2f);
    uint4 pk;
    pk.x = (unsigned int)f2bf(out[0]) | ((unsigned int)f2bf(out[1]) << 16);
    pk.y = (unsigned int)f2bf(out[2]) | ((unsigned int)f2bf(out[3]) << 16);
    pk.z = (unsigned int)f2bf(out[4]) | ((unsigned int)f2bf(out[5]) << 16);
    pk.w = (unsigned int)f2bf(out[6]) | ((unsigned int)f2bf(out[7]) << 16);
    *reinterpret_cast<uint4*>(rbpk + (size_t)e * 4) = pk;
}

// ---------------------------------------------------------------------------
// CSR offsets from sorted edge_src
// ---------------------------------------------------------------------------
__global__ __launch_bounds__(256) void row_start_kernel(
    const int* __restrict__ src, int* __restrict__ row)
{
    int i = blockIdx.x * blockDim.x + threadIdx.x;
    if (i > N_NODES) return;
    int lo = 0, hi = N_EDGES;
    while (lo < hi) {
        int mid = (lo + hi) >> 1;
        if (src[mid] < i) lo = mid + 1; else hi = mid;
    }
    row[i] = lo;
}

// ---------------------------------------------------------------------------
// xi = W_species[species]
// ---------------------------------------------------------------------------
__global__ __launch_bounds__(256) void xi_init_kernel(
    const int* __restrict__ species,
    const float* __restrict__ Wsp,
    float* __restrict__ xi)
{
    int idx = blockIdx.x * blockDim.x + threadIdx.x;
    if (idx >= N_NODES * 16) return;
    int node = idx >> 4;
    int c4 = idx & 15;
    int sp = species[node];
    reinterpret_cast<float4*>(xi)[idx] =
        reinterpret_cast<const float4*>(Wsp + (size_t)sp * 64)[c4];
}

// ---------------------------------------------------------------------------
// Pack FC weights -> bf16 B-fragment layout for mfma_f32_16x16x32_bf16.
// ---------------------------------------------------------------------------
__global__ __launch_bounds__(256) void pack_w_kernel(
    const float* __restrict__ fcW1,
    const float* __restrict__ fcW2,
    const float* __restrict__ fcW3,
    u16* __restrict__ Wpk)
{
    int idx = blockIdx.x * 256 + threadIdx.x;
    if (idx >= 3 * WPK_LAYER) return;
    int layer = idx / WPK_LAYER;
    int r = idx - layer * WPK_LAYER;
    float val = 0.0f;
    if (r < W1PK) {
        int e = r;
        int j = e & 7, lane = (e >> 3) & 63, c16 = (e >> 9) & 3, ks = e >> 11;
        int k = ks * 32 + (lane >> 4) * 8 + j;
        int colm = c16 * 16 + (lane & 15);
        if (k < 640) {
            int ss = k / 40, rem = k - ss * 40;
            int nn = rem / 5, bb = rem - nn * 5;
            val = fcW1[(size_t)layer * 656 * 64 + (size_t)(nn * 80 + ss * 5 + bb) * 64 + colm];
        } else if (k < 656) {
            val = fcW1[(size_t)layer * 656 * 64 + (size_t)k * 64 + colm];
        }
    } else {
        bool is2 = (r < W1PK + W23PK);
        const float* W = is2 ? fcW2 : fcW3;
        int e = is2 ? (r - W1PK) : (r - W1PK - W23PK);
        int j = e & 7, lane = (e >> 3) & 63, c16 = (e >> 9) & 3, ks = e >> 11;
        int k = ks * 32 + (lane >> 4) * 8 + j;
        int colm = c16 * 16 + (lane & 15);
        val = W[(size_t)layer * 64 * 64 + (size_t)k * 64 + colm];
    }
    Wpk[(size_t)layer * WPK_LAYER + r] = f2bf(val);
}

// ---------------------------------------------------------------------------
// h = xi @ Wl[l] + bl[l]   (N x 32).  float4 stores.
// ---------------------------------------------------------------------------
__global__ __launch_bounds__(256) void h_kernel(
    const float* __restrict__ xi,
    const float* __restrict__ Wl,
    const float* __restrict__ bl,
    float* __restrict__ h)
{
    __shared__ float xs[32 * 64];
    __shared__ float ws[64 * 32];
    int tid = threadIdx.x;
    int nb = blockIdx.x * 32;

    const float4* xsrc = reinterpret_cast<const float4*>(xi + (size_t)nb * 64);
    float4* xd = reinterpret_cast<float4*>(xs);
    #pragma unroll
    for (int i = 0; i < 2; ++i) xd[tid + i * 256] = xsrc[tid + i * 256];
    const float4* wsrc = reinterpret_cast<const float4*>(Wl);
    float4* wd = reinterpret_cast<float4*>(ws);
    #pragma unroll
    for (int i = 0; i < 2; ++i) wd[tid + i * 256] = wsrc[tid + i * 256];
    __syncthreads();

    int c4g = tid & 7;     // col group (4 cols)
    int nrow = tid >> 3;   // node within tile (0..31)
    float4 acc = *reinterpret_cast<const float4*>(bl + c4g * 4);
    const float* xr = xs + nrow * 64;
    #pragma unroll 8
    for (int j = 0; j < 64; ++j) {
        float xv = xr[j];
        float4 wv = *reinterpret_cast<const float4*>(ws + j * 32 + c4g * 4);
        acc.x = fmaf(xv, wv.x, acc.x);
        acc.y = fmaf(xv, wv.y, acc.y);
        acc.z = fmaf(xv, wv.z, acc.z);
        acc.w = fmaf(xv, wv.w, acc.w);
    }
    *reinterpret_cast<float4*>(h + (size_t)(nb + nrow) * 32 + c4g * 4) = acc;
}

// ---------------------------------------------------------------------------
// Aggregation: one wave per node. lane = (es 0..3)<<4 | (s 0..15).
// CRITICAL (rule #20): acc[] is only ever indexed with COMPILE-TIME constants;
// the per-lane feature selection uses a cndmask tree, not acc[es*10+m].
// R3-R5's 330MB WRITE_SIZE was acc[] spilled to scratch by runtime indexing.
// ---------------------------------------------------------------------------
__global__ __launch_bounds__(256) void agg_kernel(
    const unsigned int* __restrict__ rbpk,  // E x 4 (bf16 pairs)
    const float* __restrict__ bo,           // E x 5
    const int* __restrict__ row,
    const int* __restrict__ dst,
    const float* __restrict__ h,            // N x 32
    u16* __restrict__ X)                    // N x 656 (bf16)
{
    __shared__ unsigned int rowbuf[4][332];   // 328 dwords used/row; 16B-aligned

    int tid = threadIdx.x;
    int wv = tid >> 6;                 // wave in block
    int wid = (blockIdx.x << 2) | wv;  // node (grid exact: 5000*4 = 20000)
    int lane = tid & 63;
    int s = lane & 15;
    int es = lane >> 4;

    int e0 = row[wid], e1 = row[wid + 1];

    float acc[40];
    #pragma unroll
    for (int j = 0; j < 40; ++j) acc[j] = 0.0f;

    for (int e = e0 + es; e < e1; e += 4) {
        int d = dst[e];
        float mi = h[(size_t)d * 32 + 16 + s];
        uint4 rv = *reinterpret_cast<const uint4*>(rbpk + (size_t)e * 4);
        const float* bp = bo + (size_t)e * 5;
        float bm0 = bp[0] * mi, bm1 = bp[1] * mi, bm2 = bp[2] * mi,
              bm3 = bp[3] * mi, bm4 = bp[4] * mi;
        float rr[8] = {bflo(rv.x), bfhi(rv.x), bflo(rv.y), bfhi(rv.y),
                       bflo(rv.z), bfhi(rv.z), bflo(rv.w), bfhi(rv.w)};
        #pragma unroll
        for (int n = 0; n < 8; ++n) {
            acc[n * 5 + 0] = fmaf(rr[n], bm0, acc[n * 5 + 0]);
            acc[n * 5 + 1] = fmaf(rr[n], bm1, acc[n * 5 + 1]);
            acc[n * 5 + 2] = fmaf(rr[n], bm2, acc[n * 5 + 2]);
            acc[n * 5 + 3] = fmaf(rr[n], bm3, acc[n * 5 + 3]);
            acc[n * 5 + 4] = fmaf(rr[n], bm4, acc[n * 5 + 4]);
        }
    }
    #pragma unroll
    for (int j = 0; j < 40; ++j) {
        acc[j] += __shfl_xor(acc[j], 16, 64);
        acc[j] += __shfl_xor(acc[j], 32, 64);
    }

    // ---- select this lane's 10 features with STATIC indices ----
    float v[10];
    bool eslo = (es & 1) != 0;
    bool eshi = (es & 2) != 0;
    #pragma unroll
    for (int m = 0; m < 10; ++m) {
        float lo = eslo ? acc[10 + m] : acc[m];
        float hi = eslo ? acc[30 + m] : acc[20 + m];
        v[m] = eshi ? hi : lo;
    }

    // ---- stage into LDS row buffer ----
    unsigned int* rb = rowbuf[wv];
    unsigned int* op = rb + (s * 20 + es * 5);
    #pragma unroll
    for (int m = 0; m < 5; ++m)
        op[m] = (unsigned int)f2bf(v[2 * m]) |
                ((unsigned int)f2bf(v[2 * m + 1]) << 16);
    // si: dwords 320..327 (16 bf16 from h[wid, 0:16])
    if (es == 2 && s < 8) {
        float v0 = h[(size_t)wid * 32 + 2 * s];
        float v1 = h[(size_t)wid * 32 + 2 * s + 1];
        rb[320 + s] = (unsigned int)f2bf(v0) | ((unsigned int)f2bf(v1) << 16);
    }
    __syncthreads();

    // ---- block-wide uint4 write-out: 4 rows = 328 x 16B, all aligned ----
    unsigned int* Xd = reinterpret_cast<unsigned int*>(X) + (size_t)(blockIdx.x << 2) * 328;
    #pragma unroll
    for (int rd = 0; rd < 2; ++rd) {
        int f = rd * 256 + tid;            // uint4 index within block region
        if (f < 328) {
            int r = f / 82;                // row (82 uint4 per 1312B row)
            int dwo = (f - r * 82) * 4;    // dword offset in row (16B-aligned)
            uint4 vv = *reinterpret_cast<const uint4*>(&rowbuf[r][dwo]);
            *reinterpret_cast<uint4*>(Xd + (size_t)f * 4) = vv;
        }
    }
}

// ---------------------------------------------------------------------------
// Fused FC chain via MFMA. Block = 256 thr = 4 waves; 16 nodes per block.
// ---------------------------------------------------------------------------
__global__ __launch_bounds__(256) void fc_kernel(
    const u16* __restrict__ X,      // N x 656 bf16
    const u16* __restrict__ Wpk,    // layer's packed weights
    const float* __restrict__ b1,
    const float* __restrict__ b2,
    const float* __restrict__ b3,
    float* __restrict__ xi)
{
    __shared__ __align__(16) u16 Y1[16 * 72];
    __shared__ __align__(16) u16 Y2[16 * 72];
    __shared__ __align__(16) float Yo[16 * 68];

    int tid = threadIdx.x;
    int w = tid >> 6;
    int l = tid & 63;
    int lrow = l & 15;
    int lk = l >> 4;
    int n0 = blockIdx.x * 16;
    int node = n0 + lrow;
    int col = w * 16 + lrow;

    const u16* Wpk1 = Wpk;
    const u16* Wpk2 = Wpk + W1PK;
    const u16* Wpk3 = Wpk + W1PK + W23PK;

    // ---- FC1: K = 656 (+16 zero-padded via packed-W zeros) ----
    f32x4 acc;
    {
        float bv = b1[col];
        acc[0] = bv; acc[1] = bv; acc[2] = bv; acc[3] = bv;
    }
    const u16* xp = X + (size_t)node * XSTR + lk * 8;
    const u16* wp = Wpk1 + ((size_t)w * 64 + l) * 8;
    #pragma unroll
    for (int ks = 0; ks < 21; ++ks) {
        short8v a = *reinterpret_cast<const short8v*>(xp + ks * 32);
        short8v b = *reinterpret_cast<const short8v*>(wp + (size_t)ks * 2048);
        acc = __builtin_amdgcn_mfma_f32_16x16x32_bf16(a, b, acc, 0, 0, 0);
    }
    #pragma unroll
    for (int q = 0; q < 4; ++q)
        Y1[(lk * 4 + q) * 72 + col] = f2bf(sspf(acc[q]));
    __syncthreads();

    // ---- FC2: K = 64 ----
    {
        float bv = b2[col];
        acc[0] = bv; acc[1] = bv; acc[2] = bv; acc[3] = bv;
    }
    #pragma unroll
    for (int ks = 0; ks < 2; ++ks) {
        short8v a = *reinterpret_cast<const short8v*>(&Y1[lrow * 72 + ks * 32 + lk * 8]);
        short8v b = *reinterpret_cast<const short8v*>(Wpk2 + ((size_t)(ks * 4 + w) * 64 + l) * 8);
        acc = __builtin_amdgcn_mfma_f32_16x16x32_bf16(a, b, acc, 0, 0, 0);
    }
    #pragma unroll
    for (int q = 0; q < 4; ++q)
        Y2[(lk * 4 + q) * 72 + col] = f2bf(sspf(acc[q]));
    __syncthreads();

    // ---- FC3: K = 64 ----
    {
        float bv = b3[col];
        acc[0] = bv; acc[1] = bv; acc[2] = bv; acc[3] = bv;
    }
    #pragma unroll
    for (int ks = 0; ks < 2; ++ks) {
        short8v a = *reinterpret_cast<const short8v*>(&Y2[lrow * 72 + ks * 32 + lk * 8]);
        short8v b = *reinterpret_cast<const short8v*>(Wpk3 + ((size_t)(ks * 4 + w) * 64 + l) * 8);
        acc = __builtin_amdgcn_mfma_f32_16x16x32_bf16(a, b, acc, 0, 0, 0);
    }
    #pragma unroll
    for (int q = 0; q < 4; ++q)
        Yo[(lk * 4 + q) * 68 + col] = acc[q];
    __syncthreads();

    // ---- residual update, float4 per lane ----
    {
        int rr = tid >> 4;      // node row 0..15
        int cc = tid & 15;      // col group (4 cols)
        float4 dv = *reinterpret_cast<const float4*>(Yo + rr * 68 + cc * 4);
        float4* xpn = reinterpret_cast<float4*>(xi + (size_t)(n0 + rr) * 64 + cc * 4);
        float4 o = *xpn;
        o.x += dv.x; o.y += dv.y; o.z += dv.z; o.w += dv.w;
        *xpn = o;
    }
}

// ---------------------------------------------------------------------------
extern "C" void kernel_launch(void* const* d_in, const int* in_sizes, int n_in,
                              void* d_out, int out_size, void* d_ws, size_t ws_size,
                              hipStream_t stream) {
    const int*   species = (const int*)d_in[0];
    const int*   esrc    = (const int*)d_in[1];
    const int*   edst    = (const int*)d_in[2];
    const float* dist    = (const float*)d_in[3];
    const float* sw      = (const float*)d_in[4];
    const float* bo      = (const float*)d_in[5];
    const float* Wsp     = (const float*)d_in[6];
    const float* Wl      = (const float*)d_in[7];
    const float* bl      = (const float*)d_in[8];
    const float* fcW1    = (const float*)d_in[9];
    const float* fcb1    = (const float*)d_in[10];
    const float* fcW2    = (const float*)d_in[11];
    const float* fcb2    = (const float*)d_in[12];
    const float* fcW3    = (const float*)d_in[13];
    const float* fcb3    = (const float*)d_in[14];
    float* xi = (float*)d_out;

    char* ws = (char*)d_ws;
    unsigned int* rbpk = (unsigned int*)ws;            //  2,560,000 B
    int*          rowp = (int*)(ws + 2560000);         //     80,128 B
    float*        h    = (float*)(ws + 2640128);       //  2,560,000 B
    u16*          X    = (u16*)(ws + 5200128);         // 26,240,064 B (+slack)
    u16*          Wpk  = (u16*)(ws + 31440192);        //    307,200 B

    hipLaunchKernelGGL(edge_rb_kernel, dim3(625), dim3(256), 0, stream,
                       dist, sw, rbpk);
    hipLaunchKernelGGL(row_start_kernel, dim3(79), dim3(256), 0, stream,
                       esrc, rowp);
    hipLaunchKernelGGL(xi_init_kernel, dim3(1250), dim3(256), 0, stream,
                       species, Wsp, xi);
    hipLaunchKernelGGL(pack_w_kernel, dim3(600), dim3(256), 0, stream,
                       fcW1, fcW2, fcW3, Wpk);

    for (int l = 0; l < 3; ++l) {
        hipLaunchKernelGGL(h_kernel, dim3(625), dim3(256), 0, stream,
                           xi, Wl + (size_t)l * 64 * 32, bl + (size_t)l * 32, h);
        hipLaunchKernelGGL(agg_kernel, dim3(5000), dim3(256), 0, stream,
                           rbpk, bo, rowp, edst, h, X);
        hipLaunchKernelGGL(fc_kernel, dim3(1250), dim3(256), 0, stream,
                           X, Wpk + (size_t)l * WPK_LAYER,
                           fcb1 + (size_t)l * 64, fcb2 + (size_t)l * 64,
                           fcb3 + (size_t)l * 64, xi);
    }
}